// Round 8
// baseline (249.825 us; speedup 1.0000x reference)
//
#include <hip/hip_runtime.h>

// PositionAttentionModule: B=2, C=64, Cr=8, N=8192
// Single-head attention: d_qk=8, d_v=64, seq=8192 per batch.
// out[b,c,m] = alpha * (sum_n softmax_n(Q[m].K[n]) * V[c,n]) + x[b,c,m]
//
// R8 = R7 inner loop (fragment-major V, barrier-free, VGPR=64) at 2x
// occupancy: block = 32 queries x 16 key-slice waves (512 keys each),
// grid 512 = 2 blocks/CU = 8 waves/SIMD (the 32-waves/CU hardware cap).
// 16-wave merge tree with level-8 split into two 4-region subrounds
// (LDS stays 33.3KB/block so both blocks fit).

#define NB   2
#define CH   64
#define CR   8
#define NPOS 8192

typedef __attribute__((ext_vector_type(8)))  __bf16 bf16x8;
typedef __attribute__((ext_vector_type(16))) float  f32x16;

__device__ inline unsigned pk_bf(float lo, float hi) {
    unsigned r;
    asm("v_cvt_pk_bf16_f32 %0, %1, %2" : "=v"(r) : "v"(lo), "v"(hi));
    return r;
}
__device__ inline unsigned short f2bf(float v) {
    return (unsigned short)(pk_bf(v, 0.f) & 0xFFFFu);
}
union U4B { uint4 u; bf16x8 b; };
__device__ inline bf16x8 as_bf(uint4 u) { U4B x; x.u = u; return x.b; }

// ---------------- projection kernel (MFMA, unchanged from R7) ----------------
__global__ __launch_bounds__(128) void proj_kernel(
    const float* __restrict__ x,
    const float* __restrict__ w_b, const float* __restrict__ b_b,
    const float* __restrict__ w_c,
    const float* __restrict__ w_d,
    unsigned short* __restrict__ Qb, unsigned short* __restrict__ Kb,
    unsigned short* __restrict__ VFb)
{
    __shared__ unsigned short wt[96 * 64];
    const int tid = threadIdx.x;
    const float L2E = 1.4426950408889634f;
    for (int j = tid; j < 4096; j += 128) wt[j] = f2bf(w_d[j]);
    for (int j = tid; j < 512; j += 128) {
        wt[64 * 64 + j] = f2bf(w_b[j] * L2E);
        wt[72 * 64 + j] = f2bf(w_c[j]);
    }
    __syncthreads();

    const int w  = tid >> 6, l = tid & 63, li = l & 31, h = l >> 5;
    const int ng = blockIdx.x * 64 + w * 32;
    const int b  = ng >> 13;
    const int n  = ng & (NPOS - 1);

    const f32x16 z16 = {0,0,0,0,0,0,0,0,0,0,0,0,0,0,0,0};

    uint4 af[3][4];
    #pragma unroll
    for (int t = 0; t < 3; ++t)
        #pragma unroll
        for (int ks = 0; ks < 4; ++ks)
            af[t][ks] = *(const uint4*)&wt[(t * 32 + li) * 64 + ks * 16 + 8 * h];

    f32x16 acc0 = z16, acc1 = z16, acc2 = z16;
    #pragma unroll
    for (int ks = 0; ks < 4; ++ks) {
        float xr[8];
        #pragma unroll
        for (int j = 0; j < 8; ++j)
            xr[j] = x[(size_t)(b * CH + ks * 16 + 8 * h + j) * NPOS + n + li];
        uint4 bf = make_uint4(pk_bf(xr[0], xr[1]), pk_bf(xr[2], xr[3]),
                              pk_bf(xr[4], xr[5]), pk_bf(xr[6], xr[7]));
        acc0 = __builtin_amdgcn_mfma_f32_32x32x16_bf16(as_bf(af[0][ks]), as_bf(bf), acc0, 0, 0, 0);
        acc1 = __builtin_amdgcn_mfma_f32_32x32x16_bf16(as_bf(af[1][ks]), as_bf(bf), acc1, 0, 0, 0);
        acc2 = __builtin_amdgcn_mfma_f32_32x32x16_bf16(as_bf(af[2][ks]), as_bf(bf), acc2, 0, 0, 0);
    }

    // V epilogue -> fragment-major
    {
        const int kb = n >> 5;
        const int ks = ((li >> 4) << 1) | ((li >> 3) & 1);
        unsigned short* vf = VFb + (size_t)b * NPOS * CH
                           + (size_t)kb * 2048 + ks * 512 + (li & 7);
        #pragma unroll
        for (int r = 0; r < 16; ++r) {
            int crow = (r & 3) + 8 * (r >> 2) + 4 * h;
            vf[crow * 8]        = f2bf(acc0[r]);
            vf[(32 + crow) * 8] = f2bf(acc1[r]);
        }
    }

    // Q/K epilogue
    {
        float bb0 = b_b[4 * h + 0] * L2E, bb1 = b_b[4 * h + 1] * L2E;
        float bb2 = b_b[4 * h + 2] * L2E, bb3 = b_b[4 * h + 3] * L2E;
        unsigned q0p = pk_bf(acc2[0] + bb0, acc2[1] + bb1);
        unsigned q1p = pk_bf(acc2[2] + bb2, acc2[3] + bb3);
        unsigned k0p = pk_bf(acc2[4], acc2[5]);
        unsigned k1p = pk_bf(acc2[6], acc2[7]);
        unsigned qa0 = q0p, qb0 = q0p, qa1 = q1p, qb1 = q1p;
        asm("v_permlane32_swap_b32 %0, %1" : "+v"(qa0), "+v"(qb0));
        asm("v_permlane32_swap_b32 %0, %1" : "+v"(qa1), "+v"(qb1));
        unsigned ka0 = k0p, kb0 = k0p, ka1 = k1p, kb1 = k1p;
        asm("v_permlane32_swap_b32 %0, %1" : "+v"(ka0), "+v"(kb0));
        asm("v_permlane32_swap_b32 %0, %1" : "+v"(ka1), "+v"(kb1));
        if (h == 0) {
            *(uint4*)(Qb + (size_t)(b * NPOS + n + li) * CR) = make_uint4(qa0, qa1, qb0, qb1);
            *(uint4*)(Kb + (size_t)(b * NPOS + n + li) * CR) = make_uint4(ka0, ka1, kb0, kb1);
        }
    }
}

// ---------------- fused MFMA flash-attention ----------------
// grid = 512 blocks (2/CU), 1024 threads = 16 waves = kh 0..15.
// Wave kh: the block's 32 queries, keys [kh*512, (kh+1)*512) as 16 chunks.
__global__ __launch_bounds__(1024, 8) void attn_kernel(
    const unsigned short* __restrict__ Qb, const unsigned short* __restrict__ Kb,
    const unsigned short* __restrict__ VFb, const float* __restrict__ x,
    const float* __restrict__ alpha, const float* __restrict__ b_d,
    float* __restrict__ out)
{
    __shared__ float mbuf[4 * 2080];   // 4 merge regions (33.3 KB)

    const int tid = threadIdx.x;
    const int l   = tid & 63;
    const int li  = l & 31;
    const int h   = l >> 5;
    const int kh  = tid >> 6;          // 0..15: key slice
    const int blk = (blockIdx.x & 7) * 64 + (blockIdx.x >> 3);   // XCD: one batch per 4 XCDs
    const int b   = blk >> 8;
    const int q0  = (blk & 255) * 32;
    const int m   = q0 + li;

    const f32x16 z16 = {0,0,0,0,0,0,0,0,0,0,0,0,0,0,0,0};
    const uint4 zero4 = make_uint4(0, 0, 0, 0);

    uint4 qf = zero4;
    if (h == 0) qf = *(const uint4*)(Qb + ((size_t)b * NPOS + m) * CR);

    f32x16 acc0 = z16, acc1 = z16;
    float dn0 = 0.f, dn1 = 0.f, dn2 = 0.f, dn3 = 0.f;

    // K rows: wave keys = kh*512 + cc*32 + li
    const unsigned short* kbp = Kb + ((size_t)b * NPOS + kh * 512 + li) * CR;
    // V fragments: ushort off = keyblock*2048 + (2j+h)*512 + ch*8 + elem
    const unsigned short* vfb = VFb + (size_t)b * NPOS * CH
                              + (size_t)kh * 16 * 2048 + h * 512 + li * 8;

#define LOADS(CC, KF, A00, A01, A10, A11) {                        \
    const unsigned short* vp_ = vfb + (size_t)(CC) * 2048;         \
    A00 = *(const uint4*)(vp_);                                    \
    A01 = *(const uint4*)(vp_ + 1024);                             \
    A10 = *(const uint4*)(vp_ + 256);                              \
    A11 = *(const uint4*)(vp_ + 1280);                             \
    if (h == 0) KF = *(const uint4*)(kbp + (size_t)(CC) * 32 * CR); }

#define COMPUTE(KF, A00, A01, A10, A11) {                                                     \
    f32x16 sv = __builtin_amdgcn_mfma_f32_32x32x16_bf16(as_bf(KF), as_bf(qf), z16, 0, 0, 0);  \
    float p0_, p1_;                                                                           \
    unsigned pa0, pa1, pb0, pb1, pc0, pc1, pd0, pd1;                                          \
    p0_ = __builtin_amdgcn_exp2f(sv[0]);  p1_ = __builtin_amdgcn_exp2f(sv[1]);                \
    dn0 += p0_ + p1_;  pa0 = pk_bf(p0_, p1_);                                                 \
    p0_ = __builtin_amdgcn_exp2f(sv[2]);  p1_ = __builtin_amdgcn_exp2f(sv[3]);                \
    dn1 += p0_ + p1_;  pa1 = pk_bf(p0_, p1_);                                                 \
    p0_ = __builtin_amdgcn_exp2f(sv[4]);  p1_ = __builtin_amdgcn_exp2f(sv[5]);                \
    dn2 += p0_ + p1_;  pb0 = pk_bf(p0_, p1_);                                                 \
    p0_ = __builtin_amdgcn_exp2f(sv[6]);  p1_ = __builtin_amdgcn_exp2f(sv[7]);                \
    dn3 += p0_ + p1_;  pb1 = pk_bf(p0_, p1_);                                                 \
    p0_ = __builtin_amdgcn_exp2f(sv[8]);  p1_ = __builtin_amdgcn_exp2f(sv[9]);                \
    dn0 += p0_ + p1_;  pc0 = pk_bf(p0_, p1_);                                                 \
    p0_ = __builtin_amdgcn_exp2f(sv[10]); p1_ = __builtin_amdgcn_exp2f(sv[11]);               \
    dn1 += p0_ + p1_;  pc1 = pk_bf(p0_, p1_);                                                 \
    p0_ = __builtin_amdgcn_exp2f(sv[12]); p1_ = __builtin_amdgcn_exp2f(sv[13]);               \
    dn2 += p0_ + p1_;  pd0 = pk_bf(p0_, p1_);                                                 \
    p0_ = __builtin_amdgcn_exp2f(sv[14]); p1_ = __builtin_amdgcn_exp2f(sv[15]);               \
    dn3 += p0_ + p1_;  pd1 = pk_bf(p0_, p1_);                                                 \
    asm("v_permlane32_swap_b32 %0, %1" : "+v"(pa0), "+v"(pb0));                               \
    asm("v_permlane32_swap_b32 %0, %1" : "+v"(pa1), "+v"(pb1));                               \
    asm("v_permlane32_swap_b32 %0, %1" : "+v"(pc0), "+v"(pd0));                               \
    asm("v_permlane32_swap_b32 %0, %1" : "+v"(pc1), "+v"(pd1));                               \
    uint4 BA = make_uint4(pa0, pa1, pb0, pb1);                                                \
    uint4 BB = make_uint4(pc0, pc1, pd0, pd1);                                                \
    acc0 = __builtin_amdgcn_mfma_f32_32x32x16_bf16(as_bf(A00), as_bf(BA), acc0, 0, 0, 0);     \
    acc0 = __builtin_amdgcn_mfma_f32_32x32x16_bf16(as_bf(A01), as_bf(BB), acc0, 0, 0, 0);     \
    acc1 = __builtin_amdgcn_mfma_f32_32x32x16_bf16(as_bf(A10), as_bf(BA), acc1, 0, 0, 0);     \
    acc1 = __builtin_amdgcn_mfma_f32_32x32x16_bf16(as_bf(A11), as_bf(BB), acc1, 0, 0, 0); }

    uint4 kfA = zero4, a00A, a01A, a10A, a11A;
    uint4 kfB = zero4, a00B, a01B, a10B, a11B;
    LOADS(0, kfA, a00A, a01A, a10A, a11A);

    for (int cc = 0; cc < 16; cc += 2) {
        LOADS(cc + 1, kfB, a00B, a01B, a10B, a11B);
        COMPUTE(kfA, a00A, a01A, a10A, a11A);
        if (cc + 2 < 16) LOADS(cc + 2, kfA, a00A, a01A, a10A, a11A);
        COMPUTE(kfB, a00B, a01B, a10B, a11B);
    }
#undef LOADS
#undef COMPUTE

    float den = (dn0 + dn1) + (dn2 + dn3);
    den += __shfl_xor(den, 32);

    // ---- 16-wave merge: level-8 in two 4-region subrounds, then 8-wave tree ----
    for (int sr = 0; sr < 2; ++sr) {
        if (kh >= 8 + 4 * sr && kh < 12 + 4 * sr) {
            float* rg = mbuf + (kh - 8 - 4 * sr) * 2080;
            #pragma unroll
            for (int r = 0; r < 16; ++r) {
                rg[r * 64 + l]        = acc0[r];
                rg[1024 + r * 64 + l] = acc1[r];
            }
            if (h == 0) rg[2048 + li] = den;
        }
        __syncthreads();
        if (kh >= 4 * sr && kh < 4 * sr + 4) {
            const float* rg = mbuf + (kh - 4 * sr) * 2080;
            #pragma unroll
            for (int r = 0; r < 16; ++r) {
                acc0[r] += rg[r * 64 + l];
                acc1[r] += rg[1024 + r * 64 + l];
            }
            if (h == 0) den += rg[2048 + li];
        }
        __syncthreads();
    }
    for (int step = 4; step >= 1; step >>= 1) {
        if (kh >= step && kh < 2 * step) {
            float* rg = mbuf + (kh - step) * 2080;
            #pragma unroll
            for (int r = 0; r < 16; ++r) {
                rg[r * 64 + l]        = acc0[r];
                rg[1024 + r * 64 + l] = acc1[r];
            }
            if (h == 0) rg[2048 + li] = den;
        }
        __syncthreads();
        if (kh < step) {
            const float* rg = mbuf + kh * 2080;
            #pragma unroll
            for (int r = 0; r < 16; ++r) {
                acc0[r] += rg[r * 64 + l];
                acc1[r] += rg[1024 + r * 64 + l];
            }
            if (h == 0) den += rg[2048 + li];
        }
        __syncthreads();
    }
    if (kh == 0) {
        float* rg = mbuf;
        #pragma unroll
        for (int r = 0; r < 16; ++r) {
            rg[r * 64 + l]        = acc0[r];
            rg[1024 + r * 64 + l] = acc1[r];
        }
        if (h == 0) rg[2048 + li] = den;
    }
    __syncthreads();

    // ---- epilogue: out = (al/den)*acc + al*b_d[c] + x (float2/thread) ----
    {
        const int c   = tid >> 4;          // 0..63
        const int q2  = (tid & 15) * 2;    // 0..30
        const int tile = c >> 5, c5 = c & 31;
        const int hh  = (c5 >> 2) & 1;
        const int r   = (c5 & 3) | ((c5 >> 3) << 2);
        const float* rg = mbuf;
        float2 a   = *(const float2*)&rg[tile * 1024 + r * 64 + 32 * hh + q2];
        float2 dnv = *(const float2*)&rg[2048 + q2];
        float  al  = alpha[0];
        float  albd = al * b_d[c];
        size_t xo  = ((size_t)(b * CH + c)) * NPOS + q0 + q2;
        float2 xv  = *(const float2*)&x[xo];
        float2 o;
        o.x = a.x * (al / dnv.x) + albd + xv.x;
        o.y = a.y * (al / dnv.y) + albd + xv.y;
        *(float2*)&out[xo] = o;
    }
}

extern "C" void kernel_launch(void* const* d_in, const int* in_sizes, int n_in,
                              void* d_out, int out_size, void* d_ws, size_t ws_size,
                              hipStream_t stream) {
    const float* x     = (const float*)d_in[0];
    const float* w_b   = (const float*)d_in[1];
    const float* b_b   = (const float*)d_in[2];
    const float* w_c   = (const float*)d_in[3];
    // d_in[4] = b_c: dropped exactly (softmax-invariant per-query constant).
    const float* w_d   = (const float*)d_in[5];
    const float* b_d   = (const float*)d_in[6];
    const float* alpha = (const float*)d_in[7];
    float* out = (float*)d_out;

    unsigned short* Qw  = (unsigned short*)d_ws;                 // 256 KB
    unsigned short* Kw  = Qw + (size_t)NB * NPOS * CR;           // 256 KB
    unsigned short* VFw = Kw + (size_t)NB * NPOS * CR;           // 2 MB (frag-major)

    proj_kernel<<<256, 128, 0, stream>>>(x, w_b, b_b, w_c, w_d, Qw, Kw, VFw);
    attn_kernel<<<NB * NPOS / 32, 1024, 0, stream>>>(Qw, Kw, VFw, x, alpha, b_d, out);
}

// Round 9
// 46.117 us; speedup vs baseline: 5.4172x; 5.4172x over previous
//
#include <hip/hip_runtime.h>

// PositionAttentionModule: B=2, C=64, Cr=8, N=8192
// Single-head attention: d_qk=8, d_v=64, seq=8192 per batch.
// out[b,c,m] = alpha * (sum_n softmax_n(Q[m].K[n]) * V[c,n]) + x[b,c,m]
//
// R9 = R8 with __launch_bounds__(1024, 4): R8's (1024,8) FORCED the
// allocator to 32 VGPRs -> scratch spills (WRITE_SIZE 690MB, 250us).
// The inner loop naturally fits 64 VGPRs (= the 8-waves/SIMD boundary),
// so declaring 4 keeps the proven allocation while the HW still runs
// 8 waves/SIMD (2 blocks/CU x 16 waves) because registers permit.

#define NB   2
#define CH   64
#define CR   8
#define NPOS 8192

typedef __attribute__((ext_vector_type(8)))  __bf16 bf16x8;
typedef __attribute__((ext_vector_type(16))) float  f32x16;

__device__ inline unsigned pk_bf(float lo, float hi) {
    unsigned r;
    asm("v_cvt_pk_bf16_f32 %0, %1, %2" : "=v"(r) : "v"(lo), "v"(hi));
    return r;
}
__device__ inline unsigned short f2bf(float v) {
    return (unsigned short)(pk_bf(v, 0.f) & 0xFFFFu);
}
union U4B { uint4 u; bf16x8 b; };
__device__ inline bf16x8 as_bf(uint4 u) { U4B x; x.u = u; return x.b; }

// ---------------- projection kernel (MFMA, unchanged) ----------------
__global__ __launch_bounds__(128) void proj_kernel(
    const float* __restrict__ x,
    const float* __restrict__ w_b, const float* __restrict__ b_b,
    const float* __restrict__ w_c,
    const float* __restrict__ w_d,
    unsigned short* __restrict__ Qb, unsigned short* __restrict__ Kb,
    unsigned short* __restrict__ VFb)
{
    __shared__ unsigned short wt[96 * 64];
    const int tid = threadIdx.x;
    const float L2E = 1.4426950408889634f;
    for (int j = tid; j < 4096; j += 128) wt[j] = f2bf(w_d[j]);
    for (int j = tid; j < 512; j += 128) {
        wt[64 * 64 + j] = f2bf(w_b[j] * L2E);
        wt[72 * 64 + j] = f2bf(w_c[j]);
    }
    __syncthreads();

    const int w  = tid >> 6, l = tid & 63, li = l & 31, h = l >> 5;
    const int ng = blockIdx.x * 64 + w * 32;
    const int b  = ng >> 13;
    const int n  = ng & (NPOS - 1);

    const f32x16 z16 = {0,0,0,0,0,0,0,0,0,0,0,0,0,0,0,0};

    uint4 af[3][4];
    #pragma unroll
    for (int t = 0; t < 3; ++t)
        #pragma unroll
        for (int ks = 0; ks < 4; ++ks)
            af[t][ks] = *(const uint4*)&wt[(t * 32 + li) * 64 + ks * 16 + 8 * h];

    f32x16 acc0 = z16, acc1 = z16, acc2 = z16;
    #pragma unroll
    for (int ks = 0; ks < 4; ++ks) {
        float xr[8];
        #pragma unroll
        for (int j = 0; j < 8; ++j)
            xr[j] = x[(size_t)(b * CH + ks * 16 + 8 * h + j) * NPOS + n + li];
        uint4 bf = make_uint4(pk_bf(xr[0], xr[1]), pk_bf(xr[2], xr[3]),
                              pk_bf(xr[4], xr[5]), pk_bf(xr[6], xr[7]));
        acc0 = __builtin_amdgcn_mfma_f32_32x32x16_bf16(as_bf(af[0][ks]), as_bf(bf), acc0, 0, 0, 0);
        acc1 = __builtin_amdgcn_mfma_f32_32x32x16_bf16(as_bf(af[1][ks]), as_bf(bf), acc1, 0, 0, 0);
        acc2 = __builtin_amdgcn_mfma_f32_32x32x16_bf16(as_bf(af[2][ks]), as_bf(bf), acc2, 0, 0, 0);
    }

    // V epilogue -> fragment-major
    {
        const int kb = n >> 5;
        const int ks = ((li >> 4) << 1) | ((li >> 3) & 1);
        unsigned short* vf = VFb + (size_t)b * NPOS * CH
                           + (size_t)kb * 2048 + ks * 512 + (li & 7);
        #pragma unroll
        for (int r = 0; r < 16; ++r) {
            int crow = (r & 3) + 8 * (r >> 2) + 4 * h;
            vf[crow * 8]        = f2bf(acc0[r]);
            vf[(32 + crow) * 8] = f2bf(acc1[r]);
        }
    }

    // Q/K epilogue
    {
        float bb0 = b_b[4 * h + 0] * L2E, bb1 = b_b[4 * h + 1] * L2E;
        float bb2 = b_b[4 * h + 2] * L2E, bb3 = b_b[4 * h + 3] * L2E;
        unsigned q0p = pk_bf(acc2[0] + bb0, acc2[1] + bb1);
        unsigned q1p = pk_bf(acc2[2] + bb2, acc2[3] + bb3);
        unsigned k0p = pk_bf(acc2[4], acc2[5]);
        unsigned k1p = pk_bf(acc2[6], acc2[7]);
        unsigned qa0 = q0p, qb0 = q0p, qa1 = q1p, qb1 = q1p;
        asm("v_permlane32_swap_b32 %0, %1" : "+v"(qa0), "+v"(qb0));
        asm("v_permlane32_swap_b32 %0, %1" : "+v"(qa1), "+v"(qb1));
        unsigned ka0 = k0p, kb0 = k0p, ka1 = k1p, kb1 = k1p;
        asm("v_permlane32_swap_b32 %0, %1" : "+v"(ka0), "+v"(kb0));
        asm("v_permlane32_swap_b32 %0, %1" : "+v"(ka1), "+v"(kb1));
        if (h == 0) {
            *(uint4*)(Qb + (size_t)(b * NPOS + n + li) * CR) = make_uint4(qa0, qa1, qb0, qb1);
            *(uint4*)(Kb + (size_t)(b * NPOS + n + li) * CR) = make_uint4(ka0, ka1, kb0, kb1);
        }
    }
}

// ---------------- fused MFMA flash-attention ----------------
// grid = 512 blocks (2/CU), 1024 threads = 16 waves = kh 0..15.
// Wave kh: the block's 32 queries, keys [kh*512, (kh+1)*512) as 16 chunks.
__global__ __launch_bounds__(1024, 4) void attn_kernel(
    const unsigned short* __restrict__ Qb, const unsigned short* __restrict__ Kb,
    const unsigned short* __restrict__ VFb, const float* __restrict__ x,
    const float* __restrict__ alpha, const float* __restrict__ b_d,
    float* __restrict__ out)
{
    __shared__ float mbuf[4 * 2080];   // 4 merge regions (33.3 KB) -> 2 blocks/CU fit

    const int tid = threadIdx.x;
    const int l   = tid & 63;
    const int li  = l & 31;
    const int h   = l >> 5;
    const int kh  = tid >> 6;          // 0..15: key slice
    const int blk = (blockIdx.x & 7) * 64 + (blockIdx.x >> 3);   // XCD swizzle
    const int b   = blk >> 8;
    const int q0  = (blk & 255) * 32;
    const int m   = q0 + li;

    const f32x16 z16 = {0,0,0,0,0,0,0,0,0,0,0,0,0,0,0,0};
    const uint4 zero4 = make_uint4(0, 0, 0, 0);

    uint4 qf = zero4;
    if (h == 0) qf = *(const uint4*)(Qb + ((size_t)b * NPOS + m) * CR);

    f32x16 acc0 = z16, acc1 = z16;
    float dn0 = 0.f, dn1 = 0.f, dn2 = 0.f, dn3 = 0.f;

    const unsigned short* kbp = Kb + ((size_t)b * NPOS + kh * 512 + li) * CR;
    const unsigned short* vfb = VFb + (size_t)b * NPOS * CH
                              + (size_t)kh * 16 * 2048 + h * 512 + li * 8;

#define LOADS(CC, KF, A00, A01, A10, A11) {                        \
    const unsigned short* vp_ = vfb + (size_t)(CC) * 2048;         \
    A00 = *(const uint4*)(vp_);                                    \
    A01 = *(const uint4*)(vp_ + 1024);                             \
    A10 = *(const uint4*)(vp_ + 256);                              \
    A11 = *(const uint4*)(vp_ + 1280);                             \
    if (h == 0) KF = *(const uint4*)(kbp + (size_t)(CC) * 32 * CR); }

#define COMPUTE(KF, A00, A01, A10, A11) {                                                     \
    f32x16 sv = __builtin_amdgcn_mfma_f32_32x32x16_bf16(as_bf(KF), as_bf(qf), z16, 0, 0, 0);  \
    float p0_, p1_;                                                                           \
    unsigned pa0, pa1, pb0, pb1, pc0, pc1, pd0, pd1;                                          \
    p0_ = __builtin_amdgcn_exp2f(sv[0]);  p1_ = __builtin_amdgcn_exp2f(sv[1]);                \
    dn0 += p0_ + p1_;  pa0 = pk_bf(p0_, p1_);                                                 \
    p0_ = __builtin_amdgcn_exp2f(sv[2]);  p1_ = __builtin_amdgcn_exp2f(sv[3]);                \
    dn1 += p0_ + p1_;  pa1 = pk_bf(p0_, p1_);                                                 \
    p0_ = __builtin_amdgcn_exp2f(sv[4]);  p1_ = __builtin_amdgcn_exp2f(sv[5]);                \
    dn2 += p0_ + p1_;  pb0 = pk_bf(p0_, p1_);                                                 \
    p0_ = __builtin_amdgcn_exp2f(sv[6]);  p1_ = __builtin_amdgcn_exp2f(sv[7]);                \
    dn3 += p0_ + p1_;  pb1 = pk_bf(p0_, p1_);                                                 \
    p0_ = __builtin_amdgcn_exp2f(sv[8]);  p1_ = __builtin_amdgcn_exp2f(sv[9]);                \
    dn0 += p0_ + p1_;  pc0 = pk_bf(p0_, p1_);                                                 \
    p0_ = __builtin_amdgcn_exp2f(sv[10]); p1_ = __builtin_amdgcn_exp2f(sv[11]);               \
    dn1 += p0_ + p1_;  pc1 = pk_bf(p0_, p1_);                                                 \
    p0_ = __builtin_amdgcn_exp2f(sv[12]); p1_ = __builtin_amdgcn_exp2f(sv[13]);               \
    dn2 += p0_ + p1_;  pd0 = pk_bf(p0_, p1_);                                                 \
    p0_ = __builtin_amdgcn_exp2f(sv[14]); p1_ = __builtin_amdgcn_exp2f(sv[15]);               \
    dn3 += p0_ + p1_;  pd1 = pk_bf(p0_, p1_);                                                 \
    asm("v_permlane32_swap_b32 %0, %1" : "+v"(pa0), "+v"(pb0));                               \
    asm("v_permlane32_swap_b32 %0, %1" : "+v"(pa1), "+v"(pb1));                               \
    asm("v_permlane32_swap_b32 %0, %1" : "+v"(pc0), "+v"(pd0));                               \
    asm("v_permlane32_swap_b32 %0, %1" : "+v"(pc1), "+v"(pd1));                               \
    uint4 BA = make_uint4(pa0, pa1, pb0, pb1);                                                \
    uint4 BB = make_uint4(pc0, pc1, pd0, pd1);                                                \
    acc0 = __builtin_amdgcn_mfma_f32_32x32x16_bf16(as_bf(A00), as_bf(BA), acc0, 0, 0, 0);     \
    acc0 = __builtin_amdgcn_mfma_f32_32x32x16_bf16(as_bf(A01), as_bf(BB), acc0, 0, 0, 0);     \
    acc1 = __builtin_amdgcn_mfma_f32_32x32x16_bf16(as_bf(A10), as_bf(BA), acc1, 0, 0, 0);     \
    acc1 = __builtin_amdgcn_mfma_f32_32x32x16_bf16(as_bf(A11), as_bf(BB), acc1, 0, 0, 0); }

    uint4 kfA = zero4, a00A, a01A, a10A, a11A;
    uint4 kfB = zero4, a00B, a01B, a10B, a11B;
    LOADS(0, kfA, a00A, a01A, a10A, a11A);

    for (int cc = 0; cc < 16; cc += 2) {
        LOADS(cc + 1, kfB, a00B, a01B, a10B, a11B);
        COMPUTE(kfA, a00A, a01A, a10A, a11A);
        if (cc + 2 < 16) LOADS(cc + 2, kfA, a00A, a01A, a10A, a11A);
        COMPUTE(kfB, a00B, a01B, a10B, a11B);
    }
#undef LOADS
#undef COMPUTE

    float den = (dn0 + dn1) + (dn2 + dn3);
    den += __shfl_xor(den, 32);

    // ---- 16-wave merge: level-8 in two 4-region subrounds, then 8-wave tree ----
    for (int sr = 0; sr < 2; ++sr) {
        if (kh >= 8 + 4 * sr && kh < 12 + 4 * sr) {
            float* rg = mbuf + (kh - 8 - 4 * sr) * 2080;
            #pragma unroll
            for (int r = 0; r < 16; ++r) {
                rg[r * 64 + l]        = acc0[r];
                rg[1024 + r * 64 + l] = acc1[r];
            }
            if (h == 0) rg[2048 + li] = den;
        }
        __syncthreads();
        if (kh >= 4 * sr && kh < 4 * sr + 4) {
            const float* rg = mbuf + (kh - 4 * sr) * 2080;
            #pragma unroll
            for (int r = 0; r < 16; ++r) {
                acc0[r] += rg[r * 64 + l];
                acc1[r] += rg[1024 + r * 64 + l];
            }
            if (h == 0) den += rg[2048 + li];
        }
        __syncthreads();
    }
    for (int step = 4; step >= 1; step >>= 1) {
        if (kh >= step && kh < 2 * step) {
            float* rg = mbuf + (kh - step) * 2080;
            #pragma unroll
            for (int r = 0; r < 16; ++r) {
                rg[r * 64 + l]        = acc0[r];
                rg[1024 + r * 64 + l] = acc1[r];
            }
            if (h == 0) rg[2048 + li] = den;
        }
        __syncthreads();
        if (kh < step) {
            const float* rg = mbuf + kh * 2080;
            #pragma unroll
            for (int r = 0; r < 16; ++r) {
                acc0[r] += rg[r * 64 + l];
                acc1[r] += rg[1024 + r * 64 + l];
            }
            if (h == 0) den += rg[2048 + li];
        }
        __syncthreads();
    }
    if (kh == 0) {
        float* rg = mbuf;
        #pragma unroll
        for (int r = 0; r < 16; ++r) {
            rg[r * 64 + l]        = acc0[r];
            rg[1024 + r * 64 + l] = acc1[r];
        }
        if (h == 0) rg[2048 + li] = den;
    }
    __syncthreads();

    // ---- epilogue: out = (al/den)*acc + al*b_d[c] + x (float2/thread) ----
    {
        const int c   = tid >> 4;          // 0..63
        const int q2  = (tid & 15) * 2;    // 0..30
        const int tile = c >> 5, c5 = c & 31;
        const int hh  = (c5 >> 2) & 1;
        const int r   = (c5 & 3) | ((c5 >> 3) << 2);
        const float* rg = mbuf;
        float2 a   = *(const float2*)&rg[tile * 1024 + r * 64 + 32 * hh + q2];
        float2 dnv = *(const float2*)&rg[2048 + q2];
        float  al  = alpha[0];
        float  albd = al * b_d[c];
        size_t xo  = ((size_t)(b * CH + c)) * NPOS + q0 + q2;
        float2 xv  = *(const float2*)&x[xo];
        float2 o;
        o.x = a.x * (al / dnv.x) + albd + xv.x;
        o.y = a.y * (al / dnv.y) + albd + xv.y;
        *(float2*)&out[xo] = o;
    }
}

extern "C" void kernel_launch(void* const* d_in, const int* in_sizes, int n_in,
                              void* d_out, int out_size, void* d_ws, size_t ws_size,
                              hipStream_t stream) {
    const float* x     = (const float*)d_in[0];
    const float* w_b   = (const float*)d_in[1];
    const float* b_b   = (const float*)d_in[2];
    const float* w_c   = (const float*)d_in[3];
    // d_in[4] = b_c: dropped exactly (softmax-invariant per-query constant).
    const float* w_d   = (const float*)d_in[5];
    const float* b_d   = (const float*)d_in[6];
    const float* alpha = (const float*)d_in[7];
    float* out = (float*)d_out;

    unsigned short* Qw  = (unsigned short*)d_ws;                 // 256 KB
    unsigned short* Kw  = Qw + (size_t)NB * NPOS * CR;           // 256 KB
    unsigned short* VFw = Kw + (size_t)NB * NPOS * CR;           // 2 MB (frag-major)

    proj_kernel<<<256, 128, 0, stream>>>(x, w_b, b_b, w_c, w_d, Qw, Kw, VFw);
    attn_kernel<<<NB * NPOS / 32, 1024, 0, stream>>>(Qw, Kw, VFw, x, alpha, b_d, out);
}